// Round 8
// baseline (442.181 us; speedup 1.0000x reference)
//
#include <hip/hip_runtime.h>
#include <stdint.h>

#define N_NODES 50000
#define N_EDGES 800000
#define D_IN    128
#define D_HID   512
#define NPAD    50048   // 391 * 128 = 782 * 64
#define SCAN_NB 196     // ceil(50000/256)

typedef __attribute__((ext_vector_type(8))) short short8;
typedef __attribute__((ext_vector_type(4))) float f32x4;

union Pack8 { unsigned short us[8]; uint4 v; };

__device__ __forceinline__ float bf2f(unsigned short u) {
    union { unsigned int i; float f; } v; v.i = ((unsigned int)u) << 16; return v.f;
}
__device__ __forceinline__ unsigned short f2bf(float f) {
    union { float f; unsigned int i; } v; v.f = f;
    unsigned int r = v.i + 0x7fffu + ((v.i >> 16) & 1u);
    return (unsigned short)(r >> 16);
}
__device__ __forceinline__ float loadP(const void* p, long i, int isf) {
    return isf ? ((const float*)p)[i] : bf2f(((const unsigned short*)p)[i]);
}
__device__ __forceinline__ uint4 pack8(float4 f0, float4 f1) {
    Pack8 p;
    p.us[0] = f2bf(f0.x); p.us[1] = f2bf(f0.y); p.us[2] = f2bf(f0.z); p.us[3] = f2bf(f0.w);
    p.us[4] = f2bf(f1.x); p.us[5] = f2bf(f1.y); p.us[6] = f2bf(f1.z); p.us[7] = f2bf(f1.w);
    return p.v;
}

// ---- fused: zero stats+counts (blocks 0..200) + detect flags (block 201) ----
__global__ void k_init(const void* __restrict__ x, const int* __restrict__ ei,
                       float* __restrict__ stats, int* __restrict__ counts,
                       int* __restrict__ flags) {
    int t = threadIdx.x;
    if (blockIdx.x < 201) {
        int i = blockIdx.x * 256 + t;
        if (i < 1280) stats[i] = 0.f;
        else if (i < 1280 + N_NODES) counts[i - 1280] = 0;
    } else {
        __shared__ int sh[2];
        if (t == 0) { sh[0] = 0; sh[1] = 1; }
        __syncthreads();
        const unsigned short* xu = (const unsigned short*)x;
        for (int i = t; i < 8192; i += 256)
            if (((xu[i] >> 7) & 0xFF) == 0xFF) sh[0] = 1;   // benign race
        for (int k = t; k < 64; k += 256)
            if (ei[2 * k + 1] != 0) sh[1] = 0;
        __syncthreads();
        if (t == 0) { flags[0] = sh[0]; flags[1] = sh[1]; }
    }
}

// ---- both weight transposes in one kernel ----
__global__ void k_transpose2(const void* __restrict__ W1, const void* __restrict__ W2,
                             unsigned short* __restrict__ w1t, unsigned short* __restrict__ w2t,
                             const int* __restrict__ flags) {
    int isf = flags[0];
    int idx = blockIdx.x * 256 + threadIdx.x;
    if (idx < D_IN * D_HID) {
        int k = idx / D_HID, n = idx % D_HID;
        w1t[n * D_IN + k] = isf ? f2bf(((const float*)W1)[idx])
                                : ((const unsigned short*)W1)[idx];
    } else {
        int j = idx - D_IN * D_HID;
        int k = j / D_IN, n = j % D_IN;
        w2t[n * D_HID + k] = isf ? f2bf(((const float*)W2)[j])
                                 : ((const unsigned short*)W2)[j];
    }
}

// ---- CSR step 1: count in-degree ----
__global__ void k_count(const int* __restrict__ ei, int* __restrict__ counts,
                        const int* __restrict__ flags) {
    int i64 = flags[1];
    int e = blockIdx.x * 256 + threadIdx.x;
    int d = i64 ? ei[2 * N_EDGES + 2 * e] : ei[N_EDGES + e];
    d = min(max(d, 0), N_NODES - 1);
    atomicAdd(&counts[d], 1);
}

// ---- CSR step 2a ----
__global__ __launch_bounds__(256) void k_scan_block(const int* __restrict__ counts,
                                                    int* __restrict__ rowptr,
                                                    int* __restrict__ partials) {
    __shared__ int a[256], b[256];
    int t = threadIdx.x;
    int idx = blockIdx.x * 256 + t;
    int c = (idx < N_NODES) ? counts[idx] : 0;
    a[t] = c;
    __syncthreads();
    int* src = a; int* dst = b;
    for (int off = 1; off < 256; off <<= 1) {
        dst[t] = src[t] + ((t >= off) ? src[t - off] : 0);
        __syncthreads();
        int* tmp = src; src = dst; dst = tmp;
    }
    if (idx < N_NODES) rowptr[idx] = src[t] - c;
    if (t == 255) partials[blockIdx.x] = src[255];
}

// ---- CSR step 2b ----
__global__ __launch_bounds__(256) void k_scan_part(int* __restrict__ partials) {
    __shared__ int a[256], b[256];
    int t = threadIdx.x;
    int c = (t < SCAN_NB) ? partials[t] : 0;
    a[t] = c;
    __syncthreads();
    int* src = a; int* dst = b;
    for (int off = 1; off < 256; off <<= 1) {
        dst[t] = src[t] + ((t >= off) ? src[t - off] : 0);
        __syncthreads();
        int* tmp = src; src = dst; dst = tmp;
    }
    if (t < SCAN_NB) partials[t] = src[t] - c;
}

// ---- CSR step 2c ----
__global__ void k_scan_add(int* __restrict__ rowptr, int* __restrict__ cursor,
                           const int* __restrict__ partials) {
    int idx = blockIdx.x * 256 + threadIdx.x;
    if (idx < N_NODES) {
        int v = rowptr[idx] + partials[blockIdx.x];
        rowptr[idx] = v;
        cursor[idx] = v;
    } else if (idx == N_NODES) {
        rowptr[N_NODES] = N_EDGES;
    }
}

// ---- CSR step 3 ----
__global__ void k_fill(const int* __restrict__ ei, int* __restrict__ cursor,
                       int* __restrict__ bucket, const int* __restrict__ flags) {
    int i64 = flags[1];
    int e = blockIdx.x * 256 + threadIdx.x;
    int s, d;
    if (i64) { s = ei[2 * e]; d = ei[2 * N_EDGES + 2 * e]; }
    else     { s = ei[e];     d = ei[N_EDGES + e]; }
    s = min(max(s, 0), N_NODES - 1);
    d = min(max(d, 0), N_NODES - 1);
    int pos = atomicAdd(&cursor[d], 1);
    bucket[pos] = s;
}

// ---- gather-sum, 4-way ILP ----
__global__ __launch_bounds__(256) void k_gather(const int* __restrict__ rowptr,
                                                const int* __restrict__ bucket,
                                                const void* __restrict__ x,
                                                float* __restrict__ agg,
                                                const int* __restrict__ flags) {
    int isf = flags[0];
    int w = threadIdx.x >> 6, lane = threadIdx.x & 63;
    int row = blockIdx.x * 4 + w;
    float a0 = 0.f, a1 = 0.f;
    if (row < N_NODES) {
        int beg = rowptr[row], end = rowptr[row + 1];
        if (isf) {
            const float* xf = (const float*)x;
            float2 v = *(const float2*)(xf + (size_t)row * D_IN + lane * 2);
            a0 = v.x; a1 = v.y;
            int j = beg;
            for (; j + 4 <= end; j += 4) {
                int s0 = bucket[j], s1 = bucket[j + 1], s2 = bucket[j + 2], s3 = bucket[j + 3];
                float2 n0 = *(const float2*)(xf + (size_t)s0 * D_IN + lane * 2);
                float2 n1 = *(const float2*)(xf + (size_t)s1 * D_IN + lane * 2);
                float2 n2 = *(const float2*)(xf + (size_t)s2 * D_IN + lane * 2);
                float2 n3 = *(const float2*)(xf + (size_t)s3 * D_IN + lane * 2);
                a0 += (n0.x + n1.x) + (n2.x + n3.x);
                a1 += (n0.y + n1.y) + (n2.y + n3.y);
            }
            for (; j < end; j++) {
                float2 n = *(const float2*)(xf + (size_t)bucket[j] * D_IN + lane * 2);
                a0 += n.x; a1 += n.y;
            }
        } else {
            const unsigned int* xu = (const unsigned int*)x;
            unsigned int u = xu[(size_t)row * 64 + lane];
            a0 = bf2f(u & 0xffff); a1 = bf2f(u >> 16);
            int j = beg;
            for (; j + 4 <= end; j += 4) {
                int s0 = bucket[j], s1 = bucket[j + 1], s2 = bucket[j + 2], s3 = bucket[j + 3];
                unsigned int u0 = xu[(size_t)s0 * 64 + lane];
                unsigned int u1 = xu[(size_t)s1 * 64 + lane];
                unsigned int u2 = xu[(size_t)s2 * 64 + lane];
                unsigned int u3 = xu[(size_t)s3 * 64 + lane];
                a0 += (bf2f(u0 & 0xffff) + bf2f(u1 & 0xffff)) + (bf2f(u2 & 0xffff) + bf2f(u3 & 0xffff));
                a1 += (bf2f(u0 >> 16) + bf2f(u1 >> 16)) + (bf2f(u2 >> 16) + bf2f(u3 >> 16));
            }
            for (; j < end; j++) {
                unsigned int n = xu[(size_t)bucket[j] * 64 + lane];
                a0 += bf2f(n & 0xffff); a1 += bf2f(n >> 16);
            }
        }
    }
    *(float2*)(agg + (size_t)row * D_IN + lane * 2) = make_float2(a0, a1);
}

// ---- pass A: GEMM1 column stats. M-tile 64 (48 KB LDS, 3 blocks/CU, 782 blocks) ----
__global__ __launch_bounds__(256) void k_g1stats(const float* __restrict__ agg,
                                                 const unsigned short* __restrict__ w1t,
                                                 const void* __restrict__ b1,
                                                 float* __restrict__ sum1,
                                                 float* __restrict__ sumsq1,
                                                 const int* __restrict__ flags) {
    __shared__ unsigned short ldsX[64 * 128];    // 16 KB
    __shared__ unsigned short ldsW[128 * 128];   // 32 KB
    int isf = flags[0];
    int t = threadIdx.x;
    int m0 = blockIdx.x * 64;
    {
        int r = t >> 2;
        const float* g = agg + (size_t)(m0 + r) * D_IN;
#pragma unroll
        for (int i = 0; i < 4; i++) {
            int chunk = (t & 3) * 4 + i;
            *(uint4*)(ldsX + r * 128 + ((chunk ^ (r & 15)) * 8)) =
                pack8(*(const float4*)(g + chunk * 8), *(const float4*)(g + chunk * 8 + 4));
        }
    }
    int wid = t >> 6, lane = t & 63;
    int wm = wid & 1, wn = wid >> 1;
    int quad = lane >> 4, l16 = lane & 15;
    int r2 = t >> 1, half = t & 1;
    for (int nb = 0; nb < 4; nb++) {
        __syncthreads();   // X staged (nb=0) / prior MFMA readers done
#pragma unroll
        for (int i = 0; i < 8; i++) {
            int chunk = half * 8 + i;
            *(uint4*)(ldsW + r2 * 128 + ((chunk ^ (r2 & 15)) * 8)) =
                *(const uint4*)(w1t + (size_t)(nb * 128 + r2) * D_IN + chunk * 8);
        }
        __syncthreads();
        f32x4 acc[2][4] = {};
#pragma unroll
        for (int ks = 0; ks < 4; ks++) {
            short8 af[2], bfr[4];
#pragma unroll
            for (int mt = 0; mt < 2; mt++) {
                int rr = wm * 32 + mt * 16 + l16;
                af[mt] = *(const short8*)(ldsX + rr * 128 + (((ks * 4 + quad) ^ (rr & 15)) * 8));
            }
#pragma unroll
            for (int nt = 0; nt < 4; nt++) {
                int nn = wn * 64 + nt * 16 + l16;
                bfr[nt] = *(const short8*)(ldsW + nn * 128 + (((ks * 4 + quad) ^ (nn & 15)) * 8));
            }
#pragma unroll
            for (int mt = 0; mt < 2; mt++)
#pragma unroll
                for (int nt = 0; nt < 4; nt++)
                    acc[mt][nt] = __builtin_amdgcn_mfma_f32_16x16x32_bf16(af[mt], bfr[nt], acc[mt][nt], 0, 0, 0);
        }
#pragma unroll
        for (int nt = 0; nt < 4; nt++) {
            int n = nb * 128 + wn * 64 + nt * 16 + l16;
            float bias = loadP(b1, n, isf);
            float s = 0.f, ss = 0.f;
#pragma unroll
            for (int mt = 0; mt < 2; mt++) {
                int Rb = m0 + wm * 32 + mt * 16 + quad * 4;
#pragma unroll
                for (int rg = 0; rg < 4; rg++) {
                    if (Rb + rg < N_NODES) {
                        float z = acc[mt][nt][rg] + bias;
                        s += z; ss += z * z;
                    }
                }
            }
            s += __shfl_xor(s, 16, 64); ss += __shfl_xor(ss, 16, 64);
            s += __shfl_xor(s, 32, 64); ss += __shfl_xor(ss, 32, 64);
            if (quad == 0) { atomicAdd(&sum1[n], s); atomicAdd(&sumsq1[n], ss); }
        }
    }
}

// ---- pass B: fused GEMM1 -> BN1+ReLU -> GEMM2. M-tile 64 (48 KB LDS, 782 blocks) ----
__global__ __launch_bounds__(256) void k_fused(const float* __restrict__ agg,
                                               const unsigned short* __restrict__ w1t,
                                               const unsigned short* __restrict__ w2t,
                                               const void* __restrict__ b1,
                                               const void* __restrict__ b2,
                                               const void* __restrict__ g1,
                                               const void* __restrict__ bb1,
                                               const float* __restrict__ sum1,
                                               const float* __restrict__ sumsq1,
                                               float* __restrict__ h2,
                                               float* __restrict__ sum2,
                                               float* __restrict__ sumsq2,
                                               const int* __restrict__ flags) {
    __shared__ unsigned short bufXP[64 * 128];   // 16 KB: X tile, then P tile
    __shared__ unsigned short bufW[128 * 128];   // 32 KB: W1 tile, then W2 tile
    int isf = flags[0];
    int t = threadIdx.x;
    int m0 = blockIdx.x * 64;
    int wid = t >> 6, lane = t & 63;
    int wm = wid & 1, wn = wid >> 1;
    int quad = lane >> 4, l16 = lane & 15;
    int r2 = t >> 1, half = t & 1;
    f32x4 acc2[2][4] = {};
    for (int nb = 0; nb < 4; nb++) {
        __syncthreads();   // prior iteration's P/W2 readers done
        {
            int r = t >> 2;
            const float* g = agg + (size_t)(m0 + r) * D_IN;
#pragma unroll
            for (int i = 0; i < 4; i++) {
                int chunk = (t & 3) * 4 + i;
                *(uint4*)(bufXP + r * 128 + ((chunk ^ (r & 15)) * 8)) =
                    pack8(*(const float4*)(g + chunk * 8), *(const float4*)(g + chunk * 8 + 4));
            }
        }
#pragma unroll
        for (int i = 0; i < 8; i++) {
            int chunk = half * 8 + i;
            *(uint4*)(bufW + r2 * 128 + ((chunk ^ (r2 & 15)) * 8)) =
                *(const uint4*)(w1t + (size_t)(nb * 128 + r2) * D_IN + chunk * 8);
        }
        __syncthreads();
        f32x4 acc1[2][4] = {};
#pragma unroll
        for (int ks = 0; ks < 4; ks++) {
            short8 af[2], bfr[4];
#pragma unroll
            for (int mt = 0; mt < 2; mt++) {
                int rr = wm * 32 + mt * 16 + l16;
                af[mt] = *(const short8*)(bufXP + rr * 128 + (((ks * 4 + quad) ^ (rr & 15)) * 8));
            }
#pragma unroll
            for (int nt = 0; nt < 4; nt++) {
                int nn = wn * 64 + nt * 16 + l16;
                bfr[nt] = *(const short8*)(bufW + nn * 128 + (((ks * 4 + quad) ^ (nn & 15)) * 8));
            }
#pragma unroll
            for (int mt = 0; mt < 2; mt++)
#pragma unroll
                for (int nt = 0; nt < 4; nt++)
                    acc1[mt][nt] = __builtin_amdgcn_mfma_f32_16x16x32_bf16(af[mt], bfr[nt], acc1[mt][nt], 0, 0, 0);
        }
        __syncthreads();   // done reading X and W1
        // BN1 + ReLU -> P (bf16) into bufXP; stage W2 into bufW
#pragma unroll
        for (int nt = 0; nt < 4; nt++) {
            int nl = wn * 64 + nt * 16 + l16;
            int n1 = nb * 128 + nl;
            float mz = sum1[n1] * (1.f / N_NODES);
            float vz = sumsq1[n1] * (1.f / N_NODES) - mz * mz;
            float inv = rsqrtf(fmaxf(vz, 0.f) + 1e-5f);
            float A = loadP(g1, n1, isf) * inv;
            float C = loadP(bb1, n1, isf) - mz * A + loadP(b1, n1, isf) * A;
            int ccw = nl >> 3, cl = nl & 7;
#pragma unroll
            for (int mt = 0; mt < 2; mt++)
#pragma unroll
                for (int rg = 0; rg < 4; rg++) {
                    int R = wm * 32 + mt * 16 + quad * 4 + rg;
                    float z = fmaxf(acc1[mt][nt][rg] * A + C, 0.f);
                    bufXP[R * 128 + ((ccw ^ (R & 15)) * 8) + cl] = f2bf(z);
                }
        }
#pragma unroll
        for (int i = 0; i < 8; i++) {
            int chunk = half * 8 + i;
            *(uint4*)(bufW + r2 * 128 + ((chunk ^ (r2 & 15)) * 8)) =
                *(const uint4*)(w2t + (size_t)r2 * D_HID + nb * 128 + chunk * 8);
        }
        __syncthreads();
#pragma unroll
        for (int ks = 0; ks < 4; ks++) {
            short8 af[2], bfr[4];
#pragma unroll
            for (int mt = 0; mt < 2; mt++) {
                int rr = wm * 32 + mt * 16 + l16;
                af[mt] = *(const short8*)(bufXP + rr * 128 + (((ks * 4 + quad) ^ (rr & 15)) * 8));
            }
#pragma unroll
            for (int nt = 0; nt < 4; nt++) {
                int nn = wn * 64 + nt * 16 + l16;
                bfr[nt] = *(const short8*)(bufW + nn * 128 + (((ks * 4 + quad) ^ (nn & 15)) * 8));
            }
#pragma unroll
            for (int mt = 0; mt < 2; mt++)
#pragma unroll
                for (int nt = 0; nt < 4; nt++)
                    acc2[mt][nt] = __builtin_amdgcn_mfma_f32_16x16x32_bf16(af[mt], bfr[nt], acc2[mt][nt], 0, 0, 0);
        }
    }
#pragma unroll
    for (int nt = 0; nt < 4; nt++) {
        int n = wn * 64 + nt * 16 + l16;   // 0..127
        float bias = loadP(b2, n, isf);
        float s = 0.f, ss = 0.f;
#pragma unroll
        for (int mt = 0; mt < 2; mt++) {
            int Rb = m0 + wm * 32 + mt * 16 + quad * 4;
#pragma unroll
            for (int rg = 0; rg < 4; rg++) {
                float z = acc2[mt][nt][rg] + bias;
                h2[(size_t)(Rb + rg) * D_IN + n] = z;
                if (Rb + rg < N_NODES) { s += z; ss += z * z; }
            }
        }
        s += __shfl_xor(s, 16, 64); ss += __shfl_xor(ss, 16, 64);
        s += __shfl_xor(s, 32, 64); ss += __shfl_xor(ss, 32, 64);
        if (quad == 0) { atomicAdd(&sum2[n], s); atomicAdd(&sumsq2[n], ss); }
    }
}

// ---- BN2 + ReLU + residual + LayerNorm -> out ----
__global__ __launch_bounds__(256) void k_final(const float* __restrict__ h2,
                                               const void* __restrict__ x,
                                               const float* __restrict__ sum2,
                                               const float* __restrict__ sumsq2,
                                               const void* __restrict__ g2,
                                               const void* __restrict__ bb2,
                                               const void* __restrict__ lng,
                                               const void* __restrict__ lnb,
                                               void* __restrict__ out,
                                               const int* __restrict__ flags) {
    int isf = flags[0];
    __shared__ float a2s[D_IN], c2s[D_IN];
    int t = threadIdx.x;
    if (t < D_IN) {
        float m = sum2[t] * (1.f / N_NODES);
        float v = sumsq2[t] * (1.f / N_NODES) - m * m;
        float inv = rsqrtf(fmaxf(v, 0.f) + 1e-5f);
        float a = loadP(g2, t, isf) * inv;
        a2s[t] = a;
        c2s[t] = loadP(bb2, t, isf) - m * a;
    }
    __syncthreads();
    int w = t >> 6, lane = t & 63;
    int row = blockIdx.x * 4 + w;
    if (row >= N_NODES) return;
    size_t base = (size_t)row * D_IN;
    float o0 = fmaxf(a2s[lane] * h2[base + lane] + c2s[lane], 0.f) + loadP(x, base + lane, isf);
    float o1 = fmaxf(a2s[lane + 64] * h2[base + 64 + lane] + c2s[lane + 64], 0.f) + loadP(x, base + 64 + lane, isf);
    float s = o0 + o1, ss = o0 * o0 + o1 * o1;
#pragma unroll
    for (int m = 1; m < 64; m <<= 1) {
        s += __shfl_xor(s, m, 64);
        ss += __shfl_xor(ss, m, 64);
    }
    float mean = s * (1.f / D_IN);
    float var = ss * (1.f / D_IN) - mean * mean;
    float inv = rsqrtf(fmaxf(var, 0.f) + 1e-5f);
    float r0 = (o0 - mean) * inv * loadP(lng, lane, isf) + loadP(lnb, lane, isf);
    float r1 = (o1 - mean) * inv * loadP(lng, lane + 64, isf) + loadP(lnb, lane + 64, isf);
    if (isf) {
        ((float*)out)[base + lane] = r0;
        ((float*)out)[base + 64 + lane] = r1;
    } else {
        ((unsigned short*)out)[base + lane] = f2bf(r0);
        ((unsigned short*)out)[base + 64 + lane] = f2bf(r1);
    }
}

extern "C" void kernel_launch(void* const* d_in, const int* in_sizes, int n_in,
                              void* d_out, int out_size, void* d_ws, size_t ws_size,
                              hipStream_t stream) {
    const void* x    = d_in[0];
    const int*  ei   = (const int*)d_in[1];
    const void* W1   = d_in[2];
    const void* b1   = d_in[3];
    const void* bn1g = d_in[4];
    const void* bn1b = d_in[5];
    const void* W2   = d_in[6];
    const void* b2   = d_in[7];
    const void* bn2g = d_in[8];
    const void* bn2b = d_in[9];
    const void* lng  = d_in[10];
    const void* lnb  = d_in[11];

    char* ws = (char*)d_ws;
    float* stats    = (float*)ws;                     // 1280 f32
    float* sum1     = stats;
    float* sumsq1   = stats + 512;
    float* sum2     = stats + 1024;
    float* sumsq2   = stats + 1152;
    int*   flags    = (int*)(ws + 5120);
    int*   partials = (int*)(ws + 5184);
    int*   rowptr   = (int*)(ws + 8192);              // 50001 ints
    int*   cursor   = (int*)(ws + 212992);            // 50000 ints
    unsigned short* w1t = (unsigned short*)(ws + 417792);
    unsigned short* w2t = (unsigned short*)(ws + 548864);
    int*   bucket = (int*)(ws + 679936);              // 800000 ints
    float* agg    = (float*)(ws + 3879936);           // NPAD*128 f32, reused as h2
    float* h2     = agg;

    k_init<<<202, 256, 0, stream>>>(x, ei, stats, cursor, flags);
    k_transpose2<<<512, 256, 0, stream>>>(W1, W2, w1t, w2t, flags);
    k_count<<<N_EDGES / 256, 256, 0, stream>>>(ei, cursor, flags);
    k_scan_block<<<SCAN_NB, 256, 0, stream>>>(cursor, rowptr, partials);
    k_scan_part<<<1, 256, 0, stream>>>(partials);
    k_scan_add<<<SCAN_NB, 256, 0, stream>>>(rowptr, cursor, partials);
    k_fill<<<N_EDGES / 256, 256, 0, stream>>>(ei, cursor, bucket, flags);
    k_gather<<<NPAD / 4, 256, 0, stream>>>(rowptr, bucket, x, agg, flags);
    k_g1stats<<<NPAD / 64, 256, 0, stream>>>(agg, w1t, b1, sum1, sumsq1, flags);
    k_fused<<<NPAD / 64, 256, 0, stream>>>(agg, w1t, w2t, b1, b2, bn1g, bn1b,
                                           sum1, sumsq1, h2, sum2, sumsq2, flags);
    k_final<<<(N_NODES + 3) / 4, 256, 0, stream>>>(h2, x, sum2, sumsq2, bn2g, bn2b, lng, lnb, d_out, flags);
}

// Round 9
// 400.941 us; speedup vs baseline: 1.1029x; 1.1029x over previous
//
#include <hip/hip_runtime.h>
#include <stdint.h>

#define N_NODES 50000
#define N_EDGES 800000
#define D_IN    128
#define D_HID   512
#define NPAD    50048   // 391 * 128
#define SCAN_NB 196     // ceil(50000/256)
#define GRAM_NB 196     // gram blocks, 256 rows each (196*256 = 50176 >= NPAD)

typedef __attribute__((ext_vector_type(8))) short short8;
typedef __attribute__((ext_vector_type(4))) float f32x4;

union Pack8 { unsigned short us[8]; uint4 v; };

__device__ __forceinline__ float bf2f(unsigned short u) {
    union { unsigned int i; float f; } v; v.i = ((unsigned int)u) << 16; return v.f;
}
__device__ __forceinline__ unsigned short f2bf(float f) {
    union { float f; unsigned int i; } v; v.f = f;
    unsigned int r = v.i + 0x7fffu + ((v.i >> 16) & 1u);
    return (unsigned short)(r >> 16);
}
__device__ __forceinline__ float loadP(const void* p, long i, int isf) {
    return isf ? ((const float*)p)[i] : bf2f(((const unsigned short*)p)[i]);
}
__device__ __forceinline__ uint4 pack8(float4 f0, float4 f1) {
    Pack8 p;
    p.us[0] = f2bf(f0.x); p.us[1] = f2bf(f0.y); p.us[2] = f2bf(f0.z); p.us[3] = f2bf(f0.w);
    p.us[4] = f2bf(f1.x); p.us[5] = f2bf(f1.y); p.us[6] = f2bf(f1.z); p.us[7] = f2bf(f1.w);
    return p.v;
}

// ---- fused: zero stats+scol+counts (blocks 0..200) + detect flags (block 201) ----
__global__ void k_init(const void* __restrict__ x, const int* __restrict__ ei,
                       float* __restrict__ stats, int* __restrict__ counts,
                       int* __restrict__ flags) {
    int t = threadIdx.x;
    if (blockIdx.x < 201) {
        int i = blockIdx.x * 256 + t;
        if (i < 1408) stats[i] = 0.f;                       // stats(1280) + scol(128)
        else if (i < 1408 + N_NODES) counts[i - 1408] = 0;
    } else {
        __shared__ int sh[2];
        if (t == 0) { sh[0] = 0; sh[1] = 1; }
        __syncthreads();
        const unsigned short* xu = (const unsigned short*)x;
        for (int i = t; i < 8192; i += 256)
            if (((xu[i] >> 7) & 0xFF) == 0xFF) sh[0] = 1;   // benign race
        for (int k = t; k < 64; k += 256)
            if (ei[2 * k + 1] != 0) sh[1] = 0;
        __syncthreads();
        if (t == 0) { flags[0] = sh[0]; flags[1] = sh[1]; }
    }
}

// ---- both weight transposes in one kernel ----
__global__ void k_transpose2(const void* __restrict__ W1, const void* __restrict__ W2,
                             unsigned short* __restrict__ w1t, unsigned short* __restrict__ w2t,
                             const int* __restrict__ flags) {
    int isf = flags[0];
    int idx = blockIdx.x * 256 + threadIdx.x;
    if (idx < D_IN * D_HID) {
        int k = idx / D_HID, n = idx % D_HID;
        w1t[n * D_IN + k] = isf ? f2bf(((const float*)W1)[idx])
                                : ((const unsigned short*)W1)[idx];
    } else {
        int j = idx - D_IN * D_HID;
        int k = j / D_IN, n = j % D_IN;
        w2t[n * D_HID + k] = isf ? f2bf(((const float*)W2)[j])
                                 : ((const unsigned short*)W2)[j];
    }
}

// ---- CSR step 1: count in-degree ----
__global__ void k_count(const int* __restrict__ ei, int* __restrict__ counts,
                        const int* __restrict__ flags) {
    int i64 = flags[1];
    int e = blockIdx.x * 256 + threadIdx.x;
    int d = i64 ? ei[2 * N_EDGES + 2 * e] : ei[N_EDGES + e];
    d = min(max(d, 0), N_NODES - 1);
    atomicAdd(&counts[d], 1);
}

// ---- CSR step 2a ----
__global__ __launch_bounds__(256) void k_scan_block(const int* __restrict__ counts,
                                                    int* __restrict__ rowptr,
                                                    int* __restrict__ partials) {
    __shared__ int a[256], b[256];
    int t = threadIdx.x;
    int idx = blockIdx.x * 256 + t;
    int c = (idx < N_NODES) ? counts[idx] : 0;
    a[t] = c;
    __syncthreads();
    int* src = a; int* dst = b;
    for (int off = 1; off < 256; off <<= 1) {
        dst[t] = src[t] + ((t >= off) ? src[t - off] : 0);
        __syncthreads();
        int* tmp = src; src = dst; dst = tmp;
    }
    if (idx < N_NODES) rowptr[idx] = src[t] - c;
    if (t == 255) partials[blockIdx.x] = src[255];
}

// ---- CSR step 2b ----
__global__ __launch_bounds__(256) void k_scan_part(int* __restrict__ partials) {
    __shared__ int a[256], b[256];
    int t = threadIdx.x;
    int c = (t < SCAN_NB) ? partials[t] : 0;
    a[t] = c;
    __syncthreads();
    int* src = a; int* dst = b;
    for (int off = 1; off < 256; off <<= 1) {
        dst[t] = src[t] + ((t >= off) ? src[t - off] : 0);
        __syncthreads();
        int* tmp = src; src = dst; dst = tmp;
    }
    if (t < SCAN_NB) partials[t] = src[t] - c;
}

// ---- CSR step 2c ----
__global__ void k_scan_add(int* __restrict__ rowptr, int* __restrict__ cursor,
                           const int* __restrict__ partials) {
    int idx = blockIdx.x * 256 + threadIdx.x;
    if (idx < N_NODES) {
        int v = rowptr[idx] + partials[blockIdx.x];
        rowptr[idx] = v;
        cursor[idx] = v;
    } else if (idx == N_NODES) {
        rowptr[N_NODES] = N_EDGES;
    }
}

// ---- CSR step 3 ----
__global__ void k_fill(const int* __restrict__ ei, int* __restrict__ cursor,
                       int* __restrict__ bucket, const int* __restrict__ flags) {
    int i64 = flags[1];
    int e = blockIdx.x * 256 + threadIdx.x;
    int s, d;
    if (i64) { s = ei[2 * e]; d = ei[2 * N_EDGES + 2 * e]; }
    else     { s = ei[e];     d = ei[N_EDGES + e]; }
    s = min(max(s, 0), N_NODES - 1);
    d = min(max(d, 0), N_NODES - 1);
    int pos = atomicAdd(&cursor[d], 1);
    bucket[pos] = s;
}

// ---- gather-sum, 4-way ILP ----
__global__ __launch_bounds__(256) void k_gather(const int* __restrict__ rowptr,
                                                const int* __restrict__ bucket,
                                                const void* __restrict__ x,
                                                float* __restrict__ agg,
                                                const int* __restrict__ flags) {
    int isf = flags[0];
    int w = threadIdx.x >> 6, lane = threadIdx.x & 63;
    int row = blockIdx.x * 4 + w;
    float a0 = 0.f, a1 = 0.f;
    if (row < N_NODES) {
        int beg = rowptr[row], end = rowptr[row + 1];
        if (isf) {
            const float* xf = (const float*)x;
            float2 v = *(const float2*)(xf + (size_t)row * D_IN + lane * 2);
            a0 = v.x; a1 = v.y;
            int j = beg;
            for (; j + 4 <= end; j += 4) {
                int s0 = bucket[j], s1 = bucket[j + 1], s2 = bucket[j + 2], s3 = bucket[j + 3];
                float2 n0 = *(const float2*)(xf + (size_t)s0 * D_IN + lane * 2);
                float2 n1 = *(const float2*)(xf + (size_t)s1 * D_IN + lane * 2);
                float2 n2 = *(const float2*)(xf + (size_t)s2 * D_IN + lane * 2);
                float2 n3 = *(const float2*)(xf + (size_t)s3 * D_IN + lane * 2);
                a0 += (n0.x + n1.x) + (n2.x + n3.x);
                a1 += (n0.y + n1.y) + (n2.y + n3.y);
            }
            for (; j < end; j++) {
                float2 n = *(const float2*)(xf + (size_t)bucket[j] * D_IN + lane * 2);
                a0 += n.x; a1 += n.y;
            }
        } else {
            const unsigned int* xu = (const unsigned int*)x;
            unsigned int u = xu[(size_t)row * 64 + lane];
            a0 = bf2f(u & 0xffff); a1 = bf2f(u >> 16);
            int j = beg;
            for (; j + 4 <= end; j += 4) {
                int s0 = bucket[j], s1 = bucket[j + 1], s2 = bucket[j + 2], s3 = bucket[j + 3];
                unsigned int u0 = xu[(size_t)s0 * 64 + lane];
                unsigned int u1 = xu[(size_t)s1 * 64 + lane];
                unsigned int u2 = xu[(size_t)s2 * 64 + lane];
                unsigned int u3 = xu[(size_t)s3 * 64 + lane];
                a0 += (bf2f(u0 & 0xffff) + bf2f(u1 & 0xffff)) + (bf2f(u2 & 0xffff) + bf2f(u3 & 0xffff));
                a1 += (bf2f(u0 >> 16) + bf2f(u1 >> 16)) + (bf2f(u2 >> 16) + bf2f(u3 >> 16));
            }
            for (; j < end; j++) {
                unsigned int n = xu[(size_t)bucket[j] * 64 + lane];
                a0 += bf2f(n & 0xffff); a1 += bf2f(n >> 16);
            }
        }
    }
    *(float2*)(agg + (size_t)row * D_IN + lane * 2) = make_float2(a0, a1);
}

// ---- column sums of agg (s = A^T 1), 196 blocks x 256 rows ----
__global__ __launch_bounds__(256) void k_colsum(const float* __restrict__ agg,
                                                float* __restrict__ scol) {
    __shared__ float red[256];
    int t = threadIdx.x;
    int c = t & 127, h = t >> 7;
    int r0 = blockIdx.x * 256 + h * 128;
    float acc = 0.f;
    for (int i = 0; i < 128; i++) {
        int row = r0 + i;
        if (row < NPAD) acc += agg[(size_t)row * D_IN + c];
    }
    red[t] = acc;
    __syncthreads();
    if (h == 0) atomicAdd(&scol[c], red[c] + red[128 + c]);
}

// ---- Gram: partial G = X_block^T X_block per 256-row block, MFMA, no atomics ----
__global__ __launch_bounds__(256) void k_gram(const float* __restrict__ agg,
                                              float* __restrict__ gpart) {
    __shared__ unsigned short XT[128 * 72];   // [col][row-in-chunk 64], stride 72, 18 KB
    int t = threadIdx.x;
    int m0 = blockIdx.x * 256;
    int wid = t >> 6, lane = t & 63;
    int wm = wid & 1, wn = wid >> 1;
    int quad = lane >> 4, l16 = lane & 15;
    f32x4 acc[4][4] = {};
    for (int ch = 0; ch < 4; ch++) {
        __syncthreads();   // prior chunk's frag readers done
        {
            int r = t >> 2;                 // 0..63: row within chunk
            int c0 = (t & 3) * 32;          // 32-col slice
            int row = m0 + ch * 64 + r;
            if (row < NPAD) {
                const float* g = agg + (size_t)row * D_IN + c0;
#pragma unroll
                for (int i = 0; i < 32; i += 4) {
                    float4 f = *(const float4*)(g + i);
                    XT[(c0 + i + 0) * 72 + r] = f2bf(f.x);
                    XT[(c0 + i + 1) * 72 + r] = f2bf(f.y);
                    XT[(c0 + i + 2) * 72 + r] = f2bf(f.z);
                    XT[(c0 + i + 3) * 72 + r] = f2bf(f.w);
                }
            } else {
#pragma unroll
                for (int i = 0; i < 32; i++) XT[(c0 + i) * 72 + r] = 0;
            }
        }
        __syncthreads();
#pragma unroll
        for (int ks = 0; ks < 2; ks++) {
            short8 af[4], bfr[4];
#pragma unroll
            for (int mt = 0; mt < 4; mt++) {
                int m = wm * 64 + mt * 16 + l16;
                af[mt] = *(const short8*)(XT + m * 72 + ks * 32 + quad * 8);
            }
#pragma unroll
            for (int nt = 0; nt < 4; nt++) {
                int n = wn * 64 + nt * 16 + l16;
                bfr[nt] = *(const short8*)(XT + n * 72 + ks * 32 + quad * 8);
            }
#pragma unroll
            for (int mt = 0; mt < 4; mt++)
#pragma unroll
                for (int nt = 0; nt < 4; nt++)
                    acc[mt][nt] = __builtin_amdgcn_mfma_f32_16x16x32_bf16(af[mt], bfr[nt], acc[mt][nt], 0, 0, 0);
        }
    }
    float* P = gpart + (size_t)blockIdx.x * 16384;
#pragma unroll
    for (int nt = 0; nt < 4; nt++) {
        int n = wn * 64 + nt * 16 + l16;
#pragma unroll
        for (int mt = 0; mt < 4; mt++) {
            int Rb = wm * 64 + mt * 16 + quad * 4;
#pragma unroll
            for (int rg = 0; rg < 4; rg++)
                P[(Rb + rg) * 128 + n] = acc[mt][nt][rg];
        }
    }
}

// ---- reduce 196 partial Grams -> G ----
__global__ void k_gram_reduce(const float* __restrict__ gpart, float* __restrict__ G) {
    int idx = blockIdx.x * 256 + threadIdx.x;   // grid 64
    float s = 0.f;
    for (int b = 0; b < GRAM_NB; b++) s += gpart[(size_t)b * 16384 + idx];
    G[idx] = s;
}

// ---- solve BN1 stats: sum1 = s.w + N b ; sumsq1 = w'Gw + 2b(s.w) + N b^2 ----
__global__ __launch_bounds__(256) void k_solve(const float* __restrict__ G,
                                               const float* __restrict__ scol,
                                               const unsigned short* __restrict__ w1t,
                                               const void* __restrict__ b1,
                                               float* __restrict__ sum1,
                                               float* __restrict__ sumsq1,
                                               const int* __restrict__ flags) {
    __shared__ float wsh[4][128];
    int isf = flags[0];
    int t = threadIdx.x, wid = t >> 6, lane = t & 63;
    int n = blockIdx.x * 4 + wid;   // grid 128 -> 512 columns
    float w0 = bf2f(w1t[n * D_IN + lane]);
    float w1 = bf2f(w1t[n * D_IN + 64 + lane]);
    wsh[wid][lane] = w0; wsh[wid][64 + lane] = w1;
    __syncthreads();
    float v0 = 0.f, v1 = 0.f;
    for (int k = 0; k < 128; k++) {
        float wk = wsh[wid][k];
        v0 += wk * G[k * 128 + lane];
        v1 += wk * G[k * 128 + 64 + lane];
    }
    float sw = scol[lane] * w0 + scol[64 + lane] * w1;
    float qq = w0 * v0 + w1 * v1;
#pragma unroll
    for (int m = 1; m < 64; m <<= 1) {
        sw += __shfl_xor(sw, m, 64);
        qq += __shfl_xor(qq, m, 64);
    }
    if (lane == 0) {
        float b = loadP(b1, n, isf);
        sum1[n] = sw + (float)N_NODES * b;
        sumsq1[n] = qq + 2.f * b * sw + (float)N_NODES * b * b;
    }
}

// ---- fused GEMM1 -> BN1+ReLU -> GEMM2 (+b2), M-tile 128 (R6 version, 74 us) ----
__global__ __launch_bounds__(256) void k_fused(const float* __restrict__ agg,
                                               const unsigned short* __restrict__ w1t,
                                               const unsigned short* __restrict__ w2t,
                                               const void* __restrict__ b1,
                                               const void* __restrict__ b2,
                                               const void* __restrict__ g1,
                                               const void* __restrict__ bb1,
                                               const float* __restrict__ sum1,
                                               const float* __restrict__ sumsq1,
                                               float* __restrict__ h2,
                                               float* __restrict__ sum2,
                                               float* __restrict__ sumsq2,
                                               const int* __restrict__ flags) {
    __shared__ unsigned short bufXP[128 * 128];
    __shared__ unsigned short bufW[128 * 128];
    int isf = flags[0];
    int t = threadIdx.x;
    int m0 = blockIdx.x * 128;
    int r = t >> 1, half = t & 1;
    int wid = t >> 6, lane = t & 63;
    int wm = wid & 1, wn = wid >> 1;
    int quad = lane >> 4, l16 = lane & 15;
    f32x4 acc2[4][4] = {};
    for (int nb = 0; nb < 4; nb++) {
        __syncthreads();
#pragma unroll
        for (int i = 0; i < 8; i++) {
            int chunk = half * 8 + i;
            int sw = ((chunk ^ (r & 15)) * 8);
            const float* g = agg + (size_t)(m0 + r) * D_IN + chunk * 8;
            *(uint4*)(bufXP + r * 128 + sw) = pack8(*(const float4*)g, *(const float4*)(g + 4));
            *(uint4*)(bufW + r * 128 + sw) = *(const uint4*)(w1t + (size_t)(nb * 128 + r) * D_IN + chunk * 8);
        }
        __syncthreads();
        f32x4 acc1[4][4] = {};
#pragma unroll
        for (int ks = 0; ks < 4; ks++) {
            short8 af[4], bfr[4];
#pragma unroll
            for (int mt = 0; mt < 4; mt++)
                af[mt] = *(const short8*)(bufXP + (wm * 64 + mt * 16 + l16) * 128 + (((ks * 4 + quad) ^ l16) * 8));
#pragma unroll
            for (int nt = 0; nt < 4; nt++)
                bfr[nt] = *(const short8*)(bufW + (wn * 64 + nt * 16 + l16) * 128 + (((ks * 4 + quad) ^ l16) * 8));
#pragma unroll
            for (int mt = 0; mt < 4; mt++)
#pragma unroll
                for (int nt = 0; nt < 4; nt++)
                    acc1[mt][nt] = __builtin_amdgcn_mfma_f32_16x16x32_bf16(af[mt], bfr[nt], acc1[mt][nt], 0, 0, 0);
        }
        __syncthreads();
#pragma unroll
        for (int nt = 0; nt < 4; nt++) {
            int nl = wn * 64 + nt * 16 + l16;
            int n1 = nb * 128 + nl;
            float mz = sum1[n1] * (1.f / N_NODES);
            float vz = sumsq1[n1] * (1.f / N_NODES) - mz * mz;
            float inv = rsqrtf(fmaxf(vz, 0.f) + 1e-5f);
            float A = loadP(g1, n1, isf) * inv;
            float C = loadP(bb1, n1, isf) - mz * A + loadP(b1, n1, isf) * A;
            int ccw = nl >> 3, cl = nl & 7;
#pragma unroll
            for (int mt = 0; mt < 4; mt++)
#pragma unroll
                for (int rg = 0; rg < 4; rg++) {
                    int R = wm * 64 + mt * 16 + quad * 4 + rg;
                    float z = fmaxf(acc1[mt][nt][rg] * A + C, 0.f);
                    bufXP[R * 128 + ((ccw ^ (R & 15)) * 8) + cl] = f2bf(z);
                }
        }
#pragma unroll
        for (int i = 0; i < 8; i++) {
            int chunk = half * 8 + i;
            *(uint4*)(bufW + r * 128 + ((chunk ^ (r & 15)) * 8)) =
                *(const uint4*)(w2t + (size_t)r * D_HID + nb * 128 + chunk * 8);
        }
        __syncthreads();
#pragma unroll
        for (int ks = 0; ks < 4; ks++) {
            short8 af[4], bfr[4];
#pragma unroll
            for (int mt = 0; mt < 4; mt++)
                af[mt] = *(const short8*)(bufXP + (wm * 64 + mt * 16 + l16) * 128 + (((ks * 4 + quad) ^ l16) * 8));
#pragma unroll
            for (int nt = 0; nt < 4; nt++)
                bfr[nt] = *(const short8*)(bufW + (wn * 64 + nt * 16 + l16) * 128 + (((ks * 4 + quad) ^ l16) * 8));
#pragma unroll
            for (int mt = 0; mt < 4; mt++)
#pragma unroll
                for (int nt = 0; nt < 4; nt++)
                    acc2[mt][nt] = __builtin_amdgcn_mfma_f32_16x16x32_bf16(af[mt], bfr[nt], acc2[mt][nt], 0, 0, 0);
        }
    }
#pragma unroll
    for (int nt = 0; nt < 4; nt++) {
        int n = wn * 64 + nt * 16 + l16;
        float bias = loadP(b2, n, isf);
        float s = 0.f, ss = 0.f;
#pragma unroll
        for (int mt = 0; mt < 4; mt++) {
            int Rb = m0 + wm * 64 + mt * 16 + quad * 4;
#pragma unroll
            for (int rg = 0; rg < 4; rg++) {
                float z = acc2[mt][nt][rg] + bias;
                h2[(size_t)(Rb + rg) * D_IN + n] = z;
                if (Rb + rg < N_NODES) { s += z; ss += z * z; }
            }
        }
        s += __shfl_xor(s, 16, 64); ss += __shfl_xor(ss, 16, 64);
        s += __shfl_xor(s, 32, 64); ss += __shfl_xor(ss, 32, 64);
        if (quad == 0) { atomicAdd(&sum2[n], s); atomicAdd(&sumsq2[n], ss); }
    }
}

// ---- BN2 + ReLU + residual + LayerNorm -> out ----
__global__ __launch_bounds__(256) void k_final(const float* __restrict__ h2,
                                               const void* __restrict__ x,
                                               const float* __restrict__ sum2,
                                               const float* __restrict__ sumsq2,
                                               const void* __restrict__ g2,
                                               const void* __restrict__ bb2,
                                               const void* __restrict__ lng,
                                               const void* __restrict__ lnb,
                                               void* __restrict__ out,
                                               const int* __restrict__ flags) {
    int isf = flags[0];
    __shared__ float a2s[D_IN], c2s[D_IN];
    int t = threadIdx.x;
    if (t < D_IN) {
        float m = sum2[t] * (1.f / N_NODES);
        float v = sumsq2[t] * (1.f / N_NODES) - m * m;
        float inv = rsqrtf(fmaxf(v, 0.f) + 1e-5f);
        float a = loadP(g2, t, isf) * inv;
        a2s[t] = a;
        c2s[t] = loadP(bb2, t, isf) - m * a;
    }
    __syncthreads();
    int w = t >> 6, lane = t & 63;
    int row = blockIdx.x * 4 + w;
    if (row >= N_NODES) return;
    size_t base = (size_t)row * D_IN;
    float o0 = fmaxf(a2s[lane] * h2[base + lane] + c2s[lane], 0.f) + loadP(x, base + lane, isf);
    float o1 = fmaxf(a2s[lane + 64] * h2[base + 64 + lane] + c2s[lane + 64], 0.f) + loadP(x, base + 64 + lane, isf);
    float s = o0 + o1, ss = o0 * o0 + o1 * o1;
#pragma unroll
    for (int m = 1; m < 64; m <<= 1) {
        s += __shfl_xor(s, m, 64);
        ss += __shfl_xor(ss, m, 64);
    }
    float mean = s * (1.f / D_IN);
    float var = ss * (1.f / D_IN) - mean * mean;
    float inv = rsqrtf(fmaxf(var, 0.f) + 1e-5f);
    float r0 = (o0 - mean) * inv * loadP(lng, lane, isf) + loadP(lnb, lane, isf);
    float r1 = (o1 - mean) * inv * loadP(lng, lane + 64, isf) + loadP(lnb, lane + 64, isf);
    if (isf) {
        ((float*)out)[base + lane] = r0;
        ((float*)out)[base + 64 + lane] = r1;
    } else {
        ((unsigned short*)out)[base + lane] = f2bf(r0);
        ((unsigned short*)out)[base + 64 + lane] = f2bf(r1);
    }
}

extern "C" void kernel_launch(void* const* d_in, const int* in_sizes, int n_in,
                              void* d_out, int out_size, void* d_ws, size_t ws_size,
                              hipStream_t stream) {
    const void* x    = d_in[0];
    const int*  ei   = (const int*)d_in[1];
    const void* W1   = d_in[2];
    const void* b1   = d_in[3];
    const void* bn1g = d_in[4];
    const void* bn1b = d_in[5];
    const void* W2   = d_in[6];
    const void* b2   = d_in[7];
    const void* bn2g = d_in[8];
    const void* bn2b = d_in[9];
    const void* lng  = d_in[10];
    const void* lnb  = d_in[11];

    // workspace layout (~42.5 MB; R7 proved ws_size >= ~80.8 MB)
    char* ws = (char*)d_ws;
    float* stats    = (float*)ws;                     // 1280 f32
    float* sum1     = stats;
    float* sumsq1   = stats + 512;
    float* sum2     = stats + 1024;
    float* sumsq2   = stats + 1152;
    float* scol     = (float*)(ws + 5120);            // 128 f32 (zeroed with stats)
    int*   flags    = (int*)(ws + 5632);              // 2 ints
    int*   partials = (int*)(ws + 5760);              // 256 ints (scan)
    int*   rowptr   = (int*)(ws + 8192);              // 50001 ints
    int*   cursor   = (int*)(ws + 212992);            // 50000 ints
    unsigned short* w1t = (unsigned short*)(ws + 417792);   // [512][128] bf16
    unsigned short* w2t = (unsigned short*)(ws + 548864);   // [128][512] bf16
    int*   bucket = (int*)(ws + 679936);              // 800000 ints
    float* agg    = (float*)(ws + 3879936);           // NPAD*128 f32, reused as h2
    float* h2     = agg;
    float* G      = (float*)(ws + 29504512);          // 128*128 f32
    float* gpart  = (float*)(ws + 29570048);          // 196 * 16384 f32 = 12.8 MB

    k_init<<<202, 256, 0, stream>>>(x, ei, stats, cursor, flags);
    k_transpose2<<<512, 256, 0, stream>>>(W1, W2, w1t, w2t, flags);
    k_count<<<N_EDGES / 256, 256, 0, stream>>>(ei, cursor, flags);
    k_scan_block<<<SCAN_NB, 256, 0, stream>>>(cursor, rowptr, partials);
    k_scan_part<<<1, 256, 0, stream>>>(partials);
    k_scan_add<<<SCAN_NB, 256, 0, stream>>>(rowptr, cursor, partials);
    k_fill<<<N_EDGES / 256, 256, 0, stream>>>(ei, cursor, bucket, flags);
    k_gather<<<NPAD / 4, 256, 0, stream>>>(rowptr, bucket, x, agg, flags);
    k_colsum<<<GRAM_NB, 256, 0, stream>>>(agg, scol);
    k_gram<<<GRAM_NB, 256, 0, stream>>>(agg, gpart);
    k_gram_reduce<<<64, 256, 0, stream>>>(gpart, G);
    k_solve<<<128, 256, 0, stream>>>(G, scol, w1t, b1, sum1, sumsq1, flags);
    k_fused<<<NPAD / 128, 256, 0, stream>>>(agg, w1t, w2t, b1, b2, bn1g, bn1b,
                                            sum1, sumsq1, h2, sum2, sumsq2, flags);
    k_final<<<(N_NODES + 3) / 4, 256, 0, stream>>>(h2, x, sum2, sumsq2, bn2g, bn2b, lng, lnb, d_out, flags);
}